// Round 17
// baseline (114.021 us; speedup 1.0000x reference)
//
#include <hip/hip_runtime.h>
#include <stdint.h>

// Binarized dense via i8 MFMA: C[r][u] = dot(sign(x[r,:]), sign(W[:,u])) + b[u]
// sign in {+1,-1} as i8 0x01/0xFF; i32 accumulation exact (|dot| <= 4096).
// v_mfma_i32_32x32x32_i8: A/B = v4i (16 i8), lane&31 = row/col, lane>>5 =
// k-16-half; C/D: col = lane&31, row = (r&3)+8*(r>>2)+4*(lane>>5).
// Layouts/maps HW-verified (rounds 12-16, absmax 0).
//
// v13 = OCCUPANCY design. Empirical law r12-r16: time scales ~1/occupancy
// (1 blk/CU = 155us, 2 blk/CU = 87us), schedule micro-structure moves <5%.
// VGPR 105-128 capped us at 4 waves/SIMD. This version halves per-thread
// registers so the HW max 8 waves/SIMD (32 waves/CU) fits:
//  - 1024-thr blocks (16 waves), wave = ONE 32x32 tile (acc 16 VGPR),
//    wave wv owns cols wv*32..+31; block = 32 rows x 512 cols; grid 512
//    -> 2 blocks/CU, 32 waves/CU. Demand ~60 <= 64-reg cap (131072/2048,
//    __launch_bounds__(1024,2)).
//  - B via named-parity register pairs from L2 (fragment-major Wb2,
//    coalesced 1KB wave loads; n5 = wv). No B in LDS.
//  - A-frags in 16 KB LDS quad-period dbuf (16 barriers); each thread
//    stages 2 float4 of x per period (f4 index t and t+1024).
//  - x read from HBM exactly once.

#define BATCH  16384
#define UNITS  512
#define KDIM   4096
#define KSTEP  64
#define NSTEP  (KDIM / KSTEP)   // 64
#define NPER   (NSTEP / 4)      // 16 quad-periods
#define MROWS  32               // rows per block

typedef int v4i  __attribute__((ext_vector_type(4)));
typedef int v16i __attribute__((ext_vector_type(16)));

// ---- pack W: f32 [4096][512] -> Wb2 fragment-major i8 +/-1 (2 MB) ----------
// 16B chunk index ((s*16 + n5)*2 + ks)*64 + lane; lane = (n&31) + 32*k16half;
// covers col n5*32+(n&31), k = s*64 + ks*32 + k16half*16 + [0..15].
__global__ __launch_bounds__(256) void pack_w_kernel(const float* __restrict__ W,
                                                     uint8_t* __restrict__ Wb2) {
    int t  = blockIdx.x * 256 + threadIdx.x;   // 0..262143
    int n  = t & 511;                          // col
    int k0 = (t >> 9) * 8;                     // 8 consecutive k
    unsigned long long m = 0;
    #pragma unroll
    for (int j = 0; j < 8; ++j) {
        float v = W[(size_t)(k0 + j) * UNITS + n];
        m |= ((v < 0.f) ? 0xFFull : 0x01ull) << (8 * j);
    }
    int s  = k0 >> 6;
    int kk = k0 & 63;
    int ks = kk >> 5;
    int hi = (kk & 31) >> 4;
    int lane = (n & 31) + 32 * hi;
    size_t a = ((((size_t)s * 16 + (n >> 5)) * 2 + ks) * 64 + lane) * 16 + (kk & 15);
    *reinterpret_cast<unsigned long long*>(Wb2 + a) = m;
}

__device__ __forceinline__ uint32_t sgn4(float4 v) {
    uint32_t b0 = v.x < 0.f ? 0xFFu : 0x01u;
    uint32_t b1 = v.y < 0.f ? 0xFFu : 0x01u;
    uint32_t b2 = v.z < 0.f ? 0xFFu : 0x01u;
    uint32_t b3 = v.w < 0.f ? 0xFFu : 0x01u;
    return b0 | (b1 << 8) | (b2 << 16) | (b3 << 24);
}

// load one step's 2 B-fragments for this wave's 32-col tile
#define LOADB2(D0, D1, S)                                                      \
    {                                                                          \
        const uint8_t* _b = bbase + (size_t)(S) * 32768;                       \
        D0 = *reinterpret_cast<const v4i*>(_b);                                \
        D1 = *reinterpret_cast<const v4i*>(_b + 1024);                         \
    }

// one K-step: A-frags (ks=0,1) of period-step SIP from buffer PB; 2 MFMA
#define CLUSTER(PB, SIP, B0, B1)                                               \
    {                                                                          \
        v4i af0 = *reinterpret_cast<const v4i*>(                               \
            &Af[(PB) * 8192 + ((SIP) * 2) * 1024 + l * 16]);                   \
        v4i af1 = *reinterpret_cast<const v4i*>(                               \
            &Af[(PB) * 8192 + ((SIP) * 2 + 1) * 1024 + l * 16]);               \
        __builtin_amdgcn_s_setprio(1);                                         \
        acc = __builtin_amdgcn_mfma_i32_32x32x32_i8(af0, B0, acc, 0, 0, 0);    \
        acc = __builtin_amdgcn_mfma_i32_32x32x32_i8(af1, B1, acc, 0, 0, 0);    \
        __builtin_amdgcn_s_setprio(0);                                         \
    }

// one quad-period: steps 4Q..4Q+3 read Af[PB]; commits A(4Q+4..+7) -> Af[PB^1]
#define PERIOD(Q, PB)                                                          \
    {                                                                          \
        LOADB2(bn0, bn1, 4 * (Q) + 1);                                         \
        CLUSTER(PB, 0, bp0, bp1);                                              \
        const int _sc0 = (4 * (Q) + 4 + sp0 < NSTEP) ? 4 * (Q) + 4 + sp0 : NSTEP - 1; \
        float4 xq0 = *reinterpret_cast<const float4*>(xp0 + (size_t)_sc0 * KSTEP);    \
        LOADB2(bp0, bp1, 4 * (Q) + 2);                                         \
        CLUSTER(PB, 1, bn0, bn1);                                              \
        const int _sc1 = (4 * (Q) + 4 + sp1 < NSTEP) ? 4 * (Q) + 4 + sp1 : NSTEP - 1; \
        float4 xq1 = *reinterpret_cast<const float4*>(xp1 + (size_t)_sc1 * KSTEP);    \
        LOADB2(bn0, bn1, 4 * (Q) + 3);                                         \
        CLUSTER(PB, 2, bp0, bp1);                                              \
        LOADB2(bp0, bp1, (4 * (Q) + 4 < NSTEP) ? 4 * (Q) + 4 : NSTEP - 1);     \
        CLUSTER(PB, 3, bn0, bn1);                                              \
        *reinterpret_cast<uint32_t*>(&Af[((PB) ^ 1) * 8192 + aw0]) = sgn4(xq0);\
        *reinterpret_cast<uint32_t*>(&Af[((PB) ^ 1) * 8192 + aw1]) = sgn4(xq1);\
        __syncthreads();                                                       \
    }

// ------------------------------- MFMA GEMM ----------------------------------
__global__ __launch_bounds__(1024, 2) void mm_kernel(const float* __restrict__ x,
                                                     const uint8_t* __restrict__ Wb2,
                                                     const float* __restrict__ bias,
                                                     float* __restrict__ C) {
    __shared__ __attribute__((aligned(16))) uint8_t Af[2 * 8 * 1024];  // 16 KB
    const int t   = threadIdx.x;
    const int l   = t & 63;
    const int wv  = t >> 6;              // wave 0..15 -> cols wv*32..+31
    const int lr  = l & 31;
    const int hi  = l >> 5;
    const int row0 = blockIdx.x * MROWS;

    // x staging: thread t stages f4 index t (period-steps 0-1) and t+1024
    // (period-steps 2-3). f: sp = f>>9, f' = f&511, row = f'>>4, ak = (f'&15)*4.
    const int sp0 = t >> 9;              // 0 or 1
    const int sp1 = (t + 1024) >> 9;     // 2 or 3
    const int fa0 = t & 511;
    const int ar0 = fa0 >> 4, ak0 = (fa0 & 15) * 4;
    // f1 & 511 == t & 511 (adding 1024 doesn't change low 9 bits of f&511?
    // (t+1024)&511 == t&511 since 1024 = 2*512) -> same row/ak, later steps.
    const int aw0 = (sp0 * 2 + (ak0 >> 5)) * 1024
                  + ((ar0 & 31) + 32 * ((ak0 >> 4) & 1)) * 16 + (ak0 & 15);
    const int aw1 = (sp1 * 2 + (ak0 >> 5)) * 1024
                  + ((ar0 & 31) + 32 * ((ak0 >> 4) & 1)) * 16 + (ak0 & 15);
    const float* xp0 = x + (size_t)(row0 + ar0) * KDIM + ak0;
    const float* xp1 = xp0;              // same row/ak, different step (sp1)
    const uint8_t* bbase = Wb2 + wv * 2048 + (size_t)l * 16;

    v16i acc;
    #pragma unroll
    for (int e = 0; e < 16; ++e) acc[e] = 0;

    v4i bp0, bp1, bn0, bn1;

    // ---- prologue: B(0); x period-0 (steps sp0, sp1); commit -> Af[0] ----
    {
        LOADB2(bp0, bp1, 0);
        float4 xq0 = *reinterpret_cast<const float4*>(xp0 + (size_t)sp0 * KSTEP);
        float4 xq1 = *reinterpret_cast<const float4*>(xp1 + (size_t)sp1 * KSTEP);
        *reinterpret_cast<uint32_t*>(&Af[aw0]) = sgn4(xq0);
        *reinterpret_cast<uint32_t*>(&Af[aw1]) = sgn4(xq1);
        __syncthreads();
    }

    #pragma unroll 1
    for (int q = 0; q < NPER; q += 2) {
        PERIOD(q,     0);
        PERIOD(q + 1, 1);
    }

    // ---- epilogue: C = acc + bias (verified C/D map) ----
    {
        const int col = wv * 32 + lr;
        const float bv = bias[col];
        #pragma unroll
        for (int r = 0; r < 16; ++r) {
            int row = row0 + (r & 3) + 8 * (r >> 2) + 4 * hi;
            C[(size_t)row * UNITS + col] = (float)acc[r] + bv;
        }
    }
}

extern "C" void kernel_launch(void* const* d_in, const int* in_sizes, int n_in,
                              void* d_out, int out_size, void* d_ws, size_t ws_size,
                              hipStream_t stream) {
    const float* x = (const float*)d_in[0];
    const float* W = (const float*)d_in[1];
    const float* b = (const float*)d_in[2];
    float* out = (float*)d_out;

    uint8_t* Wb2 = (uint8_t*)d_ws;   // 2 MB fragment-major packed W

    pack_w_kernel<<<(512 * 512) / 256, 256, 0, stream>>>(W, Wb2);
    mm_kernel<<<BATCH / MROWS, 1024, 0, stream>>>(x, Wb2, b, out);
}

// Round 18
// 104.641 us; speedup vs baseline: 1.0896x; 1.0896x over previous
//
#include <hip/hip_runtime.h>
#include <stdint.h>

// Binarized dense via i8 MFMA: C[r][u] = dot(sign(x[r,:]), sign(W[:,u])) + b[u]
// sign in {+1,-1} as i8 0x01/0xFF; i32 accumulation exact (|dot| <= 4096).
// v_mfma_i32_32x32x32_i8: A/B = v4i (16 i8), lane&31 = row/col, lane>>5 =
// k-16-half; C/D: col = lane&31, row = (r&3)+8*(r>>2)+4*(lane>>5).
// Layouts/maps HW-verified (rounds 12-17, absmax 0).
//
// v14 = v13 occupancy design with GUARANTEED register headroom.
// r17's failure attributed to knife-edge VGPR (demand ~63 vs cap 64 -> spill).
// At 8 waves/SIMD, TLP replaces ILP: B-fragments are loaded ON DEMAND right
// before each MFMA cluster (no parity prefetch; other waves hide the ~250cy
// L2 latency). Demand: acc 16 + B 8 + xq 8 + af 8 + addr ~12 = ~52 <= 64.
//  - 1024-thr blocks (16 waves), wave = ONE 32x32 tile, wv owns cols
//    wv*32..+31; block = 32 rows x 512 cols; grid 512 -> 2 blocks/CU,
//    32 waves/CU (HW max). __launch_bounds__(1024,2) -> 64-VGPR cap.
//  - B from L2 (fragment-major Wb2, coalesced 1KB wave loads). No B in LDS.
//  - A-frags in 16 KB LDS quad-period dbuf (16 barriers/kernel).
//  - x read from HBM exactly once (substantially L3-resident in practice).

#define BATCH  16384
#define UNITS  512
#define KDIM   4096
#define KSTEP  64
#define NSTEP  (KDIM / KSTEP)   // 64
#define NPER   (NSTEP / 4)      // 16 quad-periods
#define MROWS  32               // rows per block

typedef int v4i  __attribute__((ext_vector_type(4)));
typedef int v16i __attribute__((ext_vector_type(16)));

// ---- pack W: f32 [4096][512] -> Wb2 fragment-major i8 +/-1 (2 MB) ----------
// 16B chunk index ((s*16 + n5)*2 + ks)*64 + lane; lane = (n&31) + 32*k16half;
// covers col n5*32+(n&31), k = s*64 + ks*32 + k16half*16 + [0..15].
__global__ __launch_bounds__(256) void pack_w_kernel(const float* __restrict__ W,
                                                     uint8_t* __restrict__ Wb2) {
    int t  = blockIdx.x * 256 + threadIdx.x;   // 0..262143
    int n  = t & 511;                          // col
    int k0 = (t >> 9) * 8;                     // 8 consecutive k
    unsigned long long m = 0;
    #pragma unroll
    for (int j = 0; j < 8; ++j) {
        float v = W[(size_t)(k0 + j) * UNITS + n];
        m |= ((v < 0.f) ? 0xFFull : 0x01ull) << (8 * j);
    }
    int s  = k0 >> 6;
    int kk = k0 & 63;
    int ks = kk >> 5;
    int hi = (kk & 31) >> 4;
    int lane = (n & 31) + 32 * hi;
    size_t a = ((((size_t)s * 16 + (n >> 5)) * 2 + ks) * 64 + lane) * 16 + (kk & 15);
    *reinterpret_cast<unsigned long long*>(Wb2 + a) = m;
}

__device__ __forceinline__ uint32_t sgn4(float4 v) {
    uint32_t b0 = v.x < 0.f ? 0xFFu : 0x01u;
    uint32_t b1 = v.y < 0.f ? 0xFFu : 0x01u;
    uint32_t b2 = v.z < 0.f ? 0xFFu : 0x01u;
    uint32_t b3 = v.w < 0.f ? 0xFFu : 0x01u;
    return b0 | (b1 << 8) | (b2 << 16) | (b3 << 24);
}

// one K-step: load this wave's 2 B-fragments (on demand, L2), A-frags of
// period-step SIP from buffer PB, 2 MFMA.
#define STEP(PB, SIP, Q)                                                       \
    {                                                                          \
        const uint8_t* _b = bbase + (size_t)(4 * (Q) + (SIP)) * 32768;         \
        v4i b0 = *reinterpret_cast<const v4i*>(_b);                            \
        v4i b1 = *reinterpret_cast<const v4i*>(_b + 1024);                     \
        v4i af0 = *reinterpret_cast<const v4i*>(                               \
            &Af[(PB) * 8192 + ((SIP) * 2) * 1024 + l * 16]);                   \
        v4i af1 = *reinterpret_cast<const v4i*>(                               \
            &Af[(PB) * 8192 + ((SIP) * 2 + 1) * 1024 + l * 16]);               \
        __builtin_amdgcn_s_setprio(1);                                         \
        acc = __builtin_amdgcn_mfma_i32_32x32x32_i8(af0, b0, acc, 0, 0, 0);    \
        acc = __builtin_amdgcn_mfma_i32_32x32x32_i8(af1, b1, acc, 0, 0, 0);    \
        __builtin_amdgcn_s_setprio(0);                                         \
    }

// one quad-period: steps 4Q..4Q+3 read Af[PB]; commits A(4Q+4..+7) -> Af[PB^1]
#define PERIOD(Q, PB)                                                          \
    {                                                                          \
        STEP(PB, 0, Q);                                                        \
        const int _sc0 = (4 * (Q) + 4 + sp0 < NSTEP) ? 4 * (Q) + 4 + sp0 : NSTEP - 1; \
        float4 xq0 = *reinterpret_cast<const float4*>(xp0 + (size_t)_sc0 * KSTEP);    \
        STEP(PB, 1, Q);                                                        \
        const int _sc1 = (4 * (Q) + 4 + sp1 < NSTEP) ? 4 * (Q) + 4 + sp1 : NSTEP - 1; \
        float4 xq1 = *reinterpret_cast<const float4*>(xp0 + (size_t)_sc1 * KSTEP);    \
        STEP(PB, 2, Q);                                                        \
        STEP(PB, 3, Q);                                                        \
        *reinterpret_cast<uint32_t*>(&Af[((PB) ^ 1) * 8192 + aw0]) = sgn4(xq0);\
        *reinterpret_cast<uint32_t*>(&Af[((PB) ^ 1) * 8192 + aw1]) = sgn4(xq1);\
        __syncthreads();                                                       \
    }

// ------------------------------- MFMA GEMM ----------------------------------
__global__ __launch_bounds__(1024, 2) void mm_kernel(const float* __restrict__ x,
                                                     const uint8_t* __restrict__ Wb2,
                                                     const float* __restrict__ bias,
                                                     float* __restrict__ C) {
    __shared__ __attribute__((aligned(16))) uint8_t Af[2 * 8 * 1024];  // 16 KB
    const int t   = threadIdx.x;
    const int l   = t & 63;
    const int wv  = t >> 6;              // wave 0..15 -> cols wv*32..+31
    const int lr  = l & 31;
    const int hi  = l >> 5;
    const int row0 = blockIdx.x * MROWS;

    // x staging (verified r17): thread t stages f4 index t (period-steps 0/1)
    // and t+1024 (period-steps 2/3); (t+1024)&511 == t&511 -> same row/ak.
    const int sp0 = t >> 9;              // 0 or 1
    const int sp1 = (t + 1024) >> 9;     // 2 or 3
    const int fa0 = t & 511;
    const int ar0 = fa0 >> 4, ak0 = (fa0 & 15) * 4;
    const int aw0 = (sp0 * 2 + (ak0 >> 5)) * 1024
                  + ((ar0 & 31) + 32 * ((ak0 >> 4) & 1)) * 16 + (ak0 & 15);
    const int aw1 = (sp1 * 2 + (ak0 >> 5)) * 1024
                  + ((ar0 & 31) + 32 * ((ak0 >> 4) & 1)) * 16 + (ak0 & 15);
    const float* xp0 = x + (size_t)(row0 + ar0) * KDIM + ak0;
    const uint8_t* bbase = Wb2 + wv * 2048 + (size_t)l * 16;

    v16i acc;
    #pragma unroll
    for (int e = 0; e < 16; ++e) acc[e] = 0;

    // ---- prologue: x period-0 (steps sp0, sp1); commit -> Af[0] ----
    {
        float4 xq0 = *reinterpret_cast<const float4*>(xp0 + (size_t)sp0 * KSTEP);
        float4 xq1 = *reinterpret_cast<const float4*>(xp0 + (size_t)sp1 * KSTEP);
        *reinterpret_cast<uint32_t*>(&Af[aw0]) = sgn4(xq0);
        *reinterpret_cast<uint32_t*>(&Af[aw1]) = sgn4(xq1);
        __syncthreads();
    }

    #pragma unroll 1
    for (int q = 0; q < NPER; q += 2) {
        PERIOD(q,     0);
        PERIOD(q + 1, 1);
    }

    // ---- epilogue: C = acc + bias (verified C/D map) ----
    {
        const int col = wv * 32 + lr;
        const float bv = bias[col];
        #pragma unroll
        for (int r = 0; r < 16; ++r) {
            int row = row0 + (r & 3) + 8 * (r >> 2) + 4 * hi;
            C[(size_t)row * UNITS + col] = (float)acc[r] + bv;
        }
    }
}

extern "C" void kernel_launch(void* const* d_in, const int* in_sizes, int n_in,
                              void* d_out, int out_size, void* d_ws, size_t ws_size,
                              hipStream_t stream) {
    const float* x = (const float*)d_in[0];
    const float* W = (const float*)d_in[1];
    const float* b = (const float*)d_in[2];
    float* out = (float*)d_out;

    uint8_t* Wb2 = (uint8_t*)d_ws;   // 2 MB fragment-major packed W

    pack_w_kernel<<<(512 * 512) / 256, 256, 0, stream>>>(W, Wb2);
    mm_kernel<<<BATCH / MROWS, 1024, 0, stream>>>(x, Wb2, b, out);
}